// Round 8
// baseline (266.173 us; speedup 1.0000x reference)
//
#include <hip/hip_runtime.h>
#include <math.h>

#define NBLK 256  // chunks/blocks for hist+scatter

typedef unsigned int uint;
typedef __attribute__((ext_vector_type(8))) short short8;
typedef __attribute__((ext_vector_type(4))) float f32x4;

__device__ __forceinline__ uint pack_bf16(float a, float b) {
    uint ua = __float_as_uint(a), ub = __float_as_uint(b);
    ua = (ua + 0x7fffu + ((ua >> 16) & 1u)) >> 16;
    ub = (ub + 0x7fffu + ((ub >> 16) & 1u)) >> 16;
    return ua | (ub << 16);
}
__device__ __forceinline__ float bf_lo(uint w) { return __uint_as_float(w << 16); }
__device__ __forceinline__ float bf_hi(uint w) { return __uint_as_float(w & 0xffff0000u); }

// ================= deterministic bucketed CSR build =================

__global__ void pass_hist(const int* __restrict__ dst, int* __restrict__ cnt,
                          int E, int nbucket, int chunk) {
    extern __shared__ int h[];
    int blk = blockIdx.x;
    for (int i = threadIdx.x; i < nbucket; i += blockDim.x) h[i] = 0;
    __syncthreads();
    int lo = blk * chunk, hi = min(lo + chunk, E);
    for (int e = lo + threadIdx.x; e < hi; e += blockDim.x)
        atomicAdd(&h[dst[e] >> 8], 1);
    __syncthreads();
    for (int i = threadIdx.x; i < nbucket; i += blockDim.x)
        cnt[i * NBLK + blk] = h[i];  // bucket-major, block-minor
}

__global__ void row_scan(int* __restrict__ cnt, int* __restrict__ totals) {
    __shared__ int lds[NBLK];
    int b = blockIdx.x, t = threadIdx.x;
    int v = cnt[b * NBLK + t];
    lds[t] = v;
    __syncthreads();
    for (int off = 1; off < NBLK; off <<= 1) {
        int y = (t >= off) ? lds[t - off] : 0;
        __syncthreads();
        lds[t] += y;
        __syncthreads();
    }
    cnt[b * NBLK + t] = lds[t] - v;
    if (t == NBLK - 1) totals[b] = lds[NBLK - 1];
}

__global__ void total_scan(int* __restrict__ totals, int nb) {
    __shared__ int lds[256];
    __shared__ int carry;
    int t = threadIdx.x;
    if (t == 0) carry = 0;
    __syncthreads();
    for (int c = 0; c < nb; c += 256) {
        int v = (c + t < nb) ? totals[c + t] : 0;
        lds[t] = v;
        __syncthreads();
        for (int off = 1; off < 256; off <<= 1) {
            int y = (t >= off) ? lds[t - off] : 0;
            __syncthreads();
            lds[t] += y;
            __syncthreads();
        }
        if (c + t < nb) totals[c + t] = carry + lds[t] - v;
        __syncthreads();
        if (t == 0) carry += lds[255];
        __syncthreads();
    }
    if (t == 0) totals[nb] = carry;
}

__global__ void pass_scatter(const int* __restrict__ src, const int* __restrict__ dst,
                             const int* __restrict__ cnt, const int* __restrict__ totals,
                             int* __restrict__ bucketed, int E, int nbucket, int chunk) {
    extern __shared__ int lcur[];
    int blk = blockIdx.x;
    for (int i = threadIdx.x; i < nbucket; i += blockDim.x)
        lcur[i] = cnt[i * NBLK + blk] + totals[i];
    __syncthreads();
    int lo = blk * chunk, hi = min(lo + chunk, E);
    for (int e = lo + threadIdx.x; e < hi; e += blockDim.x) {
        int s = src[e], d = dst[e];
        int pos = atomicAdd(&lcur[d >> 8], 1);
        bucketed[pos] = (s << 8) | (d & 255);
    }
}

__global__ void bucket_finalize(const int* __restrict__ bucketed, const int* __restrict__ totals,
                                int* __restrict__ rowptr, int* __restrict__ rowend,
                                float* __restrict__ dinv, int* __restrict__ csr_src, int n) {
    __shared__ int deg[256], sc[256], lcur[256];
    int b = blockIdx.x, t = threadIdx.x;
    int base = totals[b], bend = totals[b + 1];
    deg[t] = 0;
    __syncthreads();
    for (int i = base + t; i < bend; i += 256)
        atomicAdd(&deg[bucketed[i] & 255], 1);
    __syncthreads();
    int v = deg[t];
    sc[t] = v;
    __syncthreads();
    for (int off = 1; off < 256; off <<= 1) {
        int y = (t >= off) ? sc[t - off] : 0;
        __syncthreads();
        sc[t] += y;
        __syncthreads();
    }
    int ex = sc[t] - v;
    lcur[t] = ex;
    int node = b * 256 + t;
    if (node < n) {
        rowptr[node] = base + ex;
        rowend[node] = base + ex + v;
        dinv[node] = rsqrtf((float)(v + 1));
    }
    __syncthreads();
    for (int i = base + t; i < bend; i += 256) {
        int p = bucketed[i];
        int pos = atomicAdd(&lcur[p & 255], 1);
        csr_src[base + pos] = p >> 8;
    }
}

// ================= feature conversion (pre-scaled by dinv, sliced) =================
// x [n][32] f32 -> xsl[2][npad][8 words] bf16, xsl row = dinv[v]*x[v][s*16..s*16+16)

__global__ void convert_x_sliced(const float* __restrict__ x, const float* __restrict__ dinv,
                                 uint* __restrict__ xsl, int n, int npad) {
    int i = blockIdx.x * blockDim.x + threadIdx.x;  // i = v*2 + s
    if (i >= n * 2) return;
    int v = i >> 1, s = i & 1;
    float di = dinv[v];
    const float* xr = x + (size_t)v * 32 + s * 16;
    uint w[8];
#pragma unroll
    for (int q = 0; q < 8; ++q) w[q] = pack_bf16(xr[2 * q] * di, xr[2 * q + 1] * di);
    uint* o = xsl + ((size_t)s * npad + v) * 8;
    uint4 u0; u0.x = w[0]; u0.y = w[1]; u0.z = w[2]; u0.w = w[3];
    uint4 u1; u1.x = w[4]; u1.y = w[5]; u1.z = w[6]; u1.w = w[7];
    *reinterpret_cast<uint4*>(o) = u0;
    *reinterpret_cast<uint4*>(o + 4) = u1;
}

// ================= LDS-staged sliced aggregation gather =================
// feat' sliced [nsl][npad][8w]; out[d] = dinv[d]*(feat'[d] + sum feat'[src]).
// Block = 64 nodes x 1 slice. CSR range of the 64-node chunk is contiguous.
// Phase 1: cooperative batch-gather of all source rows into LDS (deep MLP).
// Phase 2: per-(node,quarter) accumulation from LDS (no global latency).

#define CAP 1280  // staged edges per window (40 KB LDS); Poisson(1024,32) never exceeds

template <int LOG_NSL>
__global__ __launch_bounds__(256) void agg_gather_staged(
    const int* __restrict__ rowptr, const int* __restrict__ csr_src,
    const float* __restrict__ dinv, const uint* __restrict__ feat,
    uint* __restrict__ out, int n, int npad, int E) {
    __shared__ uint stage[CAP * 8];
    __shared__ int rp[65];
    int bid = blockIdx.x;
    int slice = bid & ((1 << LOG_NSL) - 1);
    int chunk = bid >> LOG_NSL;
    int node0 = chunk * 64;
    int t = threadIdx.x;
    if (t < 65) {
        int v = node0 + t;
        rp[t] = (v < n) ? rowptr[v] : E;
    }
    __syncthreads();
    const uint* fs = feat + (size_t)slice * npad * 8;
    uint* os = out + (size_t)slice * npad * 8;
    int v4 = t >> 2;                 // node slot 0..63
    int q = (t & 3) * 2;             // word offset within 8-word row
    int node = node0 + v4;
    bool active = node < n;
    float a0 = 0.f, a1 = 0.f, a2 = 0.f, a3 = 0.f;
    if (active) {
        uint2 w = *reinterpret_cast<const uint2*>(fs + (size_t)node * 8 + q);
        a0 = bf_lo(w.x); a1 = bf_hi(w.x); a2 = bf_lo(w.y); a3 = bf_hi(w.y);
    }
    int rbeg = rp[0], rend = rp[64];
    int myrp = rp[v4], myre = rp[v4 + 1];
    for (int w0 = rbeg; w0 < rend; w0 += CAP) {
        int w1 = min(w0 + CAP, rend);
        int m = w1 - w0;
        // ---- phase 1: batch gather to LDS (indices first, then all loads) ----
        int idx[5];
#pragma unroll
        for (int j = 0; j < 5; ++j) {
            int i = t + j * 256;
            idx[j] = (i < m) ? csr_src[w0 + i] : -1;
        }
        uint4 ra[5], rb[5];
#pragma unroll
        for (int j = 0; j < 5; ++j) {
            if (idx[j] >= 0) {
                const uint* p = fs + (size_t)idx[j] * 8;
                ra[j] = *reinterpret_cast<const uint4*>(p);
                rb[j] = *reinterpret_cast<const uint4*>(p + 4);
            }
        }
#pragma unroll
        for (int j = 0; j < 5; ++j) {
            if (idx[j] >= 0) {
                int i = t + j * 256;
                *reinterpret_cast<uint4*>(&stage[i * 8]) = ra[j];
                *reinterpret_cast<uint4*>(&stage[i * 8 + 4]) = rb[j];
            }
        }
        __syncthreads();
        // ---- phase 2: accumulate from LDS ----
        int k0 = max(myrp, w0), k1 = min(myre, w1);
        for (int k = k0; k < k1; ++k) {
            uint2 u = *reinterpret_cast<const uint2*>(&stage[(k - w0) * 8 + q]);
            a0 += bf_lo(u.x); a1 += bf_hi(u.x);
            a2 += bf_lo(u.y); a3 += bf_hi(u.y);
        }
        __syncthreads();
    }
    if (active) {
        float di = dinv[node];
        uint2 o;
        o.x = pack_bf16(a0 * di, a1 * di);
        o.y = pack_bf16(a2 * di, a3 * di);
        *reinterpret_cast<uint2*>(os + (size_t)node * 8 + q) = o;
    }
}

// ================= MFMA dense layers =================
// Fragment layouts (gfx950 16x16x32 bf16, verified m89 mapping):
//  A: lane l, elem j -> A[l&15][(l>>4)*8 + j]
//  B: lane l, elem j -> B[(l>>4)*8 + j][l&15]
//  D: lane l, reg  r -> D[(l>>4)*4 + r][l&15]

__device__ __forceinline__ short8 make_bfrag(const float* __restrict__ W, int kbase, int col) {
    uint w0 = pack_bf16(W[(kbase + 0) * 64 + col], W[(kbase + 1) * 64 + col]);
    uint w1 = pack_bf16(W[(kbase + 2) * 64 + col], W[(kbase + 3) * 64 + col]);
    uint w2 = pack_bf16(W[(kbase + 4) * 64 + col], W[(kbase + 5) * 64 + col]);
    uint w3 = pack_bf16(W[(kbase + 6) * 64 + col], W[(kbase + 7) * 64 + col]);
    uint4 u; u.x = w0; u.y = w1; u.z = w2; u.w = w3;
    return __builtin_bit_cast(short8, u);
}

// h1' = dinv*relu(A@W1 + b1); A sliced [2][npad][8w] (K=32); out sliced [4][npad][8w]
__global__ __launch_bounds__(256) void gemm1_mfma(const uint* __restrict__ A,
                                                  const float* __restrict__ W,
                                                  const float* __restrict__ bias,
                                                  const float* __restrict__ dinv,
                                                  uint* __restrict__ outw, int n, int npad) {
    int t = threadIdx.x;
    int lane = t & 63, wv = t >> 6;
    int rowbase = blockIdx.x * 64 + wv * 16;
    int r16 = lane & 15, g4 = lane >> 4;
    short8 a = __builtin_bit_cast(short8, *reinterpret_cast<const uint4*>(
        A + ((size_t)(g4 >> 1) * npad + rowbase + r16) * 8 + (g4 & 1) * 4));
    int kbase = g4 * 8;
    float dr[4];
#pragma unroll
    for (int r = 0; r < 4; ++r) {
        int row = rowbase + g4 * 4 + r;
        dr[r] = (row < n) ? dinv[row] : 0.f;
    }
#pragma unroll
    for (int nt = 0; nt < 4; ++nt) {
        int col = nt * 16 + r16;
        short8 b = make_bfrag(W, kbase, col);
        f32x4 z = {0.f, 0.f, 0.f, 0.f};
        f32x4 acc = __builtin_amdgcn_mfma_f32_16x16x32_bf16(a, b, z, 0, 0, 0);
        float bcol = bias[col];
#pragma unroll
        for (int r = 0; r < 4; ++r) {
            int row = rowbase + g4 * 4 + r;
            float v = fmaxf(acc[r] + bcol, 0.f) * dr[r];
            float o = __shfl_xor(v, 1);
            if ((lane & 1) == 0)
                outw[((size_t)nt * npad + row) * 8 + (r16 >> 1)] = pack_bf16(v, o);
        }
    }
}

// pool[j] += sum_rows relu(A@W2 + b2); A sliced [4][npad][8w] (K=64); h2 never stored
__global__ __launch_bounds__(256) void gemm2_mfma_pool(const uint* __restrict__ A,
                                                       const float* __restrict__ W,
                                                       const float* __restrict__ bias,
                                                       float* __restrict__ g, int n, int npad) {
    __shared__ float sblk[64];
    int t = threadIdx.x;
    if (t < 64) sblk[t] = 0.f;
    __syncthreads();
    int lane = t & 63, wv = t >> 6;
    int rowbase = blockIdx.x * 64 + wv * 16;
    int r16 = lane & 15, g4 = lane >> 4;
    size_t roff = (size_t)(rowbase + r16) * 8 + (g4 & 1) * 4;
    size_t sstride = (size_t)npad * 8;
    short8 a0 = __builtin_bit_cast(short8,
        *reinterpret_cast<const uint4*>(A + (size_t)(g4 >> 1) * sstride + roff));
    short8 a1 = __builtin_bit_cast(short8,
        *reinterpret_cast<const uint4*>(A + (size_t)(2 + (g4 >> 1)) * sstride + roff));
#pragma unroll
    for (int nt = 0; nt < 4; ++nt) {
        int col = nt * 16 + r16;
        short8 b0 = make_bfrag(W, g4 * 8, col);
        short8 b1 = make_bfrag(W, 32 + g4 * 8, col);
        f32x4 z = {0.f, 0.f, 0.f, 0.f};
        f32x4 acc = __builtin_amdgcn_mfma_f32_16x16x32_bf16(a0, b0, z, 0, 0, 0);
        acc = __builtin_amdgcn_mfma_f32_16x16x32_bf16(a1, b1, acc, 0, 0, 0);
        float bcol = bias[col];
        float part = 0.f;
#pragma unroll
        for (int r = 0; r < 4; ++r) {
            int row = rowbase + g4 * 4 + r;
            float v = fmaxf(acc[r] + bcol, 0.f);
            part += (row < n) ? v : 0.f;
        }
        atomicAdd(&sblk[col], part);
    }
    __syncthreads();
    if (t < 64) atomicAdd(&g[t], sblk[t]);
}

__global__ void final_head(const float* __restrict__ g, const float* __restrict__ Wfc,
                           const float* __restrict__ bfc, float* __restrict__ out, int n) {
    __shared__ float logits[5];
    int t = threadIdx.x;
    if (t < 5) {
        float acc = bfc[t];
        float invn = 1.0f / (float)n;
        for (int k = 0; k < 64; ++k) acc += (g[k] * invn) * Wfc[k * 5 + t];
        logits[t] = acc;
    }
    __syncthreads();
    if (t == 0) {
        float m = logits[0];
        for (int i = 1; i < 5; ++i) m = fmaxf(m, logits[i]);
        float s = 0.0f;
        for (int i = 0; i < 5; ++i) s += expf(logits[i] - m);
        float lse = m + logf(s);
        for (int i = 0; i < 5; ++i) out[i] = logits[i] - lse;
    }
}

// ================= launch =================

extern "C" void kernel_launch(void* const* d_in, const int* in_sizes, int n_in,
                              void* d_out, int out_size, void* d_ws, size_t ws_size,
                              hipStream_t stream) {
    const float* x   = (const float*)d_in[0];
    const int*   ei  = (const int*)d_in[1];
    const float* W1  = (const float*)d_in[2];
    const float* b1  = (const float*)d_in[3];
    const float* W2  = (const float*)d_in[4];
    const float* b2  = (const float*)d_in[5];
    const float* Wfc = (const float*)d_in[6];
    const float* bfc = (const float*)d_in[7];
    float* out = (float*)d_out;

    const int n = in_sizes[0] / 32;   // 100000
    const int E = in_sizes[1] / 2;    // 1600000
    const int* src = ei;
    const int* dst = ei + E;
    const int npad = (n + 63) & ~63;
    const int nbucket = (n + 255) >> 8;
    const int chunk = (E + NBLK - 1) / NBLK;
    const int nchunk = (n + 63) / 64;

    // workspace carve-up (4-byte units)
    int*   csr_src = (int*)d_ws;                        // [E]
    int*   rowptr  = csr_src + E;                       // [n]
    int*   rowend  = rowptr + n;                        // [n]
    float* dinv    = (float*)(rowend + n);              // [n]
    int*   cnt     = (int*)(dinv + n);                  // [nbucket*NBLK]
    int*   totals  = cnt + (size_t)nbucket * NBLK;      // [nbucket+1]
    size_t offw    = (size_t)(totals + nbucket + 1 - (int*)d_ws);
    offw           = (offw + 3) & ~(size_t)3;           // 16B align
    uint*  xsl     = (uint*)d_ws + offw;                // [2*npad*8]
    uint*  agg1    = xsl + (size_t)2 * npad * 8;        // [2*npad*8]
    uint*  h1sl    = agg1 + (size_t)2 * npad * 8;       // [4*npad*8]
    uint*  agg2    = h1sl + (size_t)4 * npad * 8;       // [4*npad*8]
    float* g       = (float*)(agg2 + (size_t)4 * npad * 8); // [64]
    int*   bucketed = (int*)agg2;                       // alias: [E] consumed pre-agg (4*npad*8 >= E)

    const int B = 256;
    const size_t lds_b = (size_t)nbucket * sizeof(int);

    // ---- build CSR + norms (no global atomics) ----
    pass_hist<<<NBLK, B, lds_b, stream>>>(dst, cnt, E, nbucket, chunk);
    row_scan<<<nbucket, NBLK, 0, stream>>>(cnt, totals);
    total_scan<<<1, B, 0, stream>>>(totals, nbucket);
    pass_scatter<<<NBLK, B, lds_b, stream>>>(src, dst, cnt, totals, bucketed, E, nbucket, chunk);
    bucket_finalize<<<nbucket, B, 0, stream>>>(bucketed, totals, rowptr, rowend, dinv, csr_src, n);

    // ---- x -> pre-scaled sliced bf16 ----
    convert_x_sliced<<<(n * 2 + B - 1) / B, B, 0, stream>>>(x, dinv, xsl, n, npad);

    // ---- layer 1: staged gather (2 slices) -> agg1; MFMA gemm -> h1' sliced [4] ----
    agg_gather_staged<1><<<nchunk * 2, B, 0, stream>>>(rowptr, csr_src, dinv, xsl, agg1,
                                                       n, npad, E);
    gemm1_mfma<<<npad / 64, B, 0, stream>>>(agg1, W1, b1, dinv, h1sl, n, npad);

    // ---- layer 2: staged gather (4 slices) -> agg2; MFMA gemm+relu+pool -> g ----
    agg_gather_staged<2><<<nchunk * 4, B, 0, stream>>>(rowptr, csr_src, dinv, h1sl, agg2,
                                                       n, npad, E);
    hipMemsetAsync(g, 0, 64 * sizeof(float), stream);
    gemm2_mfma_pool<<<npad / 64, B, 0, stream>>>(agg2, W2, b2, g, n, npad);

    // ---- head ----
    final_head<<<1, 64, 0, stream>>>(g, Wfc, bfc, out, n);
}

// Round 9
// 172.538 us; speedup vs baseline: 1.5427x; 1.5427x over previous
//
#include <hip/hip_runtime.h>
#include <math.h>

#define NBLK 256  // chunks/blocks for hist+scatter

typedef unsigned int uint;
typedef __attribute__((ext_vector_type(8))) short short8;
typedef __attribute__((ext_vector_type(4))) float f32x4;

__device__ __forceinline__ uint pack_bf16(float a, float b) {
    uint ua = __float_as_uint(a), ub = __float_as_uint(b);
    ua = (ua + 0x7fffu + ((ua >> 16) & 1u)) >> 16;
    ub = (ub + 0x7fffu + ((ub >> 16) & 1u)) >> 16;
    return ua | (ub << 16);
}
__device__ __forceinline__ float bf_lo(uint w) { return __uint_as_float(w << 16); }
__device__ __forceinline__ float bf_hi(uint w) { return __uint_as_float(w & 0xffff0000u); }

// ================= deterministic bucketed CSR build =================

__global__ void pass_hist(const int* __restrict__ dst, int* __restrict__ cnt,
                          int E, int nbucket, int chunk) {
    extern __shared__ int h[];
    int blk = blockIdx.x;
    for (int i = threadIdx.x; i < nbucket; i += blockDim.x) h[i] = 0;
    __syncthreads();
    int lo = blk * chunk, hi = min(lo + chunk, E);
    for (int e = lo + threadIdx.x; e < hi; e += blockDim.x)
        atomicAdd(&h[dst[e] >> 8], 1);
    __syncthreads();
    for (int i = threadIdx.x; i < nbucket; i += blockDim.x)
        cnt[i * NBLK + blk] = h[i];  // bucket-major, block-minor
}

__global__ void row_scan(int* __restrict__ cnt, int* __restrict__ totals) {
    __shared__ int lds[NBLK];
    int b = blockIdx.x, t = threadIdx.x;
    int v = cnt[b * NBLK + t];
    lds[t] = v;
    __syncthreads();
    for (int off = 1; off < NBLK; off <<= 1) {
        int y = (t >= off) ? lds[t - off] : 0;
        __syncthreads();
        lds[t] += y;
        __syncthreads();
    }
    cnt[b * NBLK + t] = lds[t] - v;
    if (t == NBLK - 1) totals[b] = lds[NBLK - 1];
}

__global__ void total_scan(int* __restrict__ totals, int nb) {
    __shared__ int lds[256];
    __shared__ int carry;
    int t = threadIdx.x;
    if (t == 0) carry = 0;
    __syncthreads();
    for (int c = 0; c < nb; c += 256) {
        int v = (c + t < nb) ? totals[c + t] : 0;
        lds[t] = v;
        __syncthreads();
        for (int off = 1; off < 256; off <<= 1) {
            int y = (t >= off) ? lds[t - off] : 0;
            __syncthreads();
            lds[t] += y;
            __syncthreads();
        }
        if (c + t < nb) totals[c + t] = carry + lds[t] - v;
        __syncthreads();
        if (t == 0) carry += lds[255];
        __syncthreads();
    }
    if (t == 0) totals[nb] = carry;
}

__global__ void pass_scatter(const int* __restrict__ src, const int* __restrict__ dst,
                             const int* __restrict__ cnt, const int* __restrict__ totals,
                             int* __restrict__ bucketed, int E, int nbucket, int chunk) {
    extern __shared__ int lcur[];
    int blk = blockIdx.x;
    for (int i = threadIdx.x; i < nbucket; i += blockDim.x)
        lcur[i] = cnt[i * NBLK + blk] + totals[i];
    __syncthreads();
    int lo = blk * chunk, hi = min(lo + chunk, E);
    for (int e = lo + threadIdx.x; e < hi; e += blockDim.x) {
        int s = src[e], d = dst[e];
        int pos = atomicAdd(&lcur[d >> 8], 1);
        bucketed[pos] = (s << 8) | (d & 255);
    }
}

__global__ void bucket_finalize(const int* __restrict__ bucketed, const int* __restrict__ totals,
                                int* __restrict__ rowptr, int* __restrict__ rowend,
                                float* __restrict__ dinv, int* __restrict__ csr_src, int n) {
    __shared__ int deg[256], sc[256], lcur[256];
    int b = blockIdx.x, t = threadIdx.x;
    int base = totals[b], bend = totals[b + 1];
    deg[t] = 0;
    __syncthreads();
    for (int i = base + t; i < bend; i += 256)
        atomicAdd(&deg[bucketed[i] & 255], 1);
    __syncthreads();
    int v = deg[t];
    sc[t] = v;
    __syncthreads();
    for (int off = 1; off < 256; off <<= 1) {
        int y = (t >= off) ? sc[t - off] : 0;
        __syncthreads();
        sc[t] += y;
        __syncthreads();
    }
    int ex = sc[t] - v;
    lcur[t] = ex;
    int node = b * 256 + t;
    if (node < n) {
        rowptr[node] = base + ex;
        rowend[node] = base + ex + v;
        dinv[node] = rsqrtf((float)(v + 1));
    }
    __syncthreads();
    for (int i = base + t; i < bend; i += 256) {
        int p = bucketed[i];
        int pos = atomicAdd(&lcur[p & 255], 1);
        csr_src[base + pos] = p >> 8;
    }
}

// ================= feature conversion (pre-scaled by dinv, sliced) =================
// x [n][32] f32 -> xsl[2][npad][8 words] bf16, xsl row = dinv[v]*x[v][s*16..s*16+16)

__global__ void convert_x_sliced(const float* __restrict__ x, const float* __restrict__ dinv,
                                 uint* __restrict__ xsl, int n, int npad) {
    int i = blockIdx.x * blockDim.x + threadIdx.x;  // i = v*2 + s
    if (i >= n * 2) return;
    int v = i >> 1, s = i & 1;
    float di = dinv[v];
    const float* xr = x + (size_t)v * 32 + s * 16;
    uint w[8];
#pragma unroll
    for (int q = 0; q < 8; ++q) w[q] = pack_bf16(xr[2 * q] * di, xr[2 * q + 1] * di);
    uint* o = xsl + ((size_t)s * npad + v) * 8;
    uint4 u0; u0.x = w[0]; u0.y = w[1]; u0.z = w[2]; u0.w = w[3];
    uint4 u1; u1.x = w[4]; u1.y = w[5]; u1.z = w[6]; u1.w = w[7];
    *reinterpret_cast<uint4*>(o) = u0;
    *reinterpret_cast<uint4*>(o + 4) = u1;
}

// ================= sliced aggregation gather (pipelined) =================
// feat' sliced [nsl][npad][8w]; out[d] = dinv[d]*(feat'[d] + sum feat'[src]).
// Block = 64 nodes x 1 slice; 4 threads/node, 8B each. slice = bid&(nsl-1)
// rides bid%8->XCD round-robin (8%nsl==0 so slice is constant per XCD ->
// one 3.2MB slice stays L2-resident per XCD).
// Inner loop: ping-pong 8-edge batches; batch B's 16 loads are in flight
// while batch A accumulates (~24 VMEM outstanding/wave vs 8 before).

#define LOADB(ID, F, BI)                                                        \
    do {                                                                        \
        int kb_ = k0 + (BI) * 8;                                                \
        _Pragma("unroll") for (int j = 0; j < 8; ++j) ID[j] = csr_src[kb_ + j]; \
        _Pragma("unroll") for (int j = 0; j < 8; ++j)                           \
            F[j] = *reinterpret_cast<const uint2*>(fs + (size_t)ID[j] * 8);     \
    } while (0)

#define ACCB(F)                                                                 \
    do {                                                                        \
        _Pragma("unroll") for (int j = 0; j < 8; ++j) {                         \
            a0 += bf_lo(F[j].x); a1 += bf_hi(F[j].x);                           \
            a2 += bf_lo(F[j].y); a3 += bf_hi(F[j].y);                           \
        }                                                                       \
    } while (0)

template <int LOG_NSL>
__global__ __launch_bounds__(256, 4) void agg_gather_sliced(
    const int* __restrict__ rowptr, const int* __restrict__ rowend,
    const int* __restrict__ csr_src, const float* __restrict__ dinv,
    const uint* __restrict__ feat, uint* __restrict__ out, int n, int npad) {
    int bid = blockIdx.x;
    int slice = bid & ((1 << LOG_NSL) - 1);
    int chunk = bid >> LOG_NSL;
    int node = chunk * 64 + (threadIdx.x >> 2);
    if (node >= n) return;
    int q = (threadIdx.x & 3) * 2;  // word offset within 8-word slice row
    const uint* fs = feat + (size_t)slice * npad * 8 + q;
    uint* os = out + (size_t)slice * npad * 8 + q;
    int k = rowptr[node], end = rowend[node];
    uint2 w = *reinterpret_cast<const uint2*>(fs + (size_t)node * 8);
    float a0 = bf_lo(w.x), a1 = bf_hi(w.x), a2 = bf_lo(w.y), a3 = bf_hi(w.y);

    int nb = (end - k) >> 3;
    int k0 = k;
    if (nb) {
        int idA[8], idB[8];
        uint2 fA[8], fB[8];
        LOADB(idA, fA, 0);
        int i = 0;
        while (true) {
            if (i + 1 < nb) LOADB(idB, fB, i + 1);
            ACCB(fA);
            ++i;
            if (i >= nb) break;
            if (i + 1 < nb) LOADB(idA, fA, i + 1);
            ACCB(fB);
            ++i;
            if (i >= nb) break;
        }
        k = k0 + nb * 8;
    }
    // tail: one 4-step then singles
    if (k + 4 <= end) {
        int s0 = csr_src[k], s1 = csr_src[k + 1], s2 = csr_src[k + 2], s3 = csr_src[k + 3];
        uint2 u0 = *reinterpret_cast<const uint2*>(fs + (size_t)s0 * 8);
        uint2 u1 = *reinterpret_cast<const uint2*>(fs + (size_t)s1 * 8);
        uint2 u2 = *reinterpret_cast<const uint2*>(fs + (size_t)s2 * 8);
        uint2 u3 = *reinterpret_cast<const uint2*>(fs + (size_t)s3 * 8);
        a0 += (bf_lo(u0.x) + bf_lo(u1.x)) + (bf_lo(u2.x) + bf_lo(u3.x));
        a1 += (bf_hi(u0.x) + bf_hi(u1.x)) + (bf_hi(u2.x) + bf_hi(u3.x));
        a2 += (bf_lo(u0.y) + bf_lo(u1.y)) + (bf_lo(u2.y) + bf_lo(u3.y));
        a3 += (bf_hi(u0.y) + bf_hi(u1.y)) + (bf_hi(u2.y) + bf_hi(u3.y));
        k += 4;
    }
    for (; k < end; ++k) {
        int s = csr_src[k];
        uint2 u = *reinterpret_cast<const uint2*>(fs + (size_t)s * 8);
        a0 += bf_lo(u.x); a1 += bf_hi(u.x); a2 += bf_lo(u.y); a3 += bf_hi(u.y);
    }
    float di = dinv[node];
    uint2 o;
    o.x = pack_bf16(a0 * di, a1 * di);
    o.y = pack_bf16(a2 * di, a3 * di);
    *reinterpret_cast<uint2*>(os + (size_t)node * 8) = o;
}

// ================= MFMA dense layers =================
// Fragment layouts (gfx950 16x16x32 bf16, verified m89 mapping):
//  A: lane l, elem j -> A[l&15][(l>>4)*8 + j]
//  B: lane l, elem j -> B[(l>>4)*8 + j][l&15]
//  D: lane l, reg  r -> D[(l>>4)*4 + r][l&15]

__device__ __forceinline__ short8 make_bfrag(const float* __restrict__ W, int kbase, int col) {
    uint w0 = pack_bf16(W[(kbase + 0) * 64 + col], W[(kbase + 1) * 64 + col]);
    uint w1 = pack_bf16(W[(kbase + 2) * 64 + col], W[(kbase + 3) * 64 + col]);
    uint w2 = pack_bf16(W[(kbase + 4) * 64 + col], W[(kbase + 5) * 64 + col]);
    uint w3 = pack_bf16(W[(kbase + 6) * 64 + col], W[(kbase + 7) * 64 + col]);
    uint4 u; u.x = w0; u.y = w1; u.z = w2; u.w = w3;
    return __builtin_bit_cast(short8, u);
}

// h1' = dinv*relu(A@W1 + b1); A sliced [2][npad][8w] (K=32); out sliced [4][npad][8w]
__global__ __launch_bounds__(256) void gemm1_mfma(const uint* __restrict__ A,
                                                  const float* __restrict__ W,
                                                  const float* __restrict__ bias,
                                                  const float* __restrict__ dinv,
                                                  uint* __restrict__ outw, int n, int npad) {
    int t = threadIdx.x;
    int lane = t & 63, wv = t >> 6;
    int rowbase = blockIdx.x * 64 + wv * 16;
    int r16 = lane & 15, g4 = lane >> 4;
    short8 a = __builtin_bit_cast(short8, *reinterpret_cast<const uint4*>(
        A + ((size_t)(g4 >> 1) * npad + rowbase + r16) * 8 + (g4 & 1) * 4));
    int kbase = g4 * 8;
    float dr[4];
#pragma unroll
    for (int r = 0; r < 4; ++r) {
        int row = rowbase + g4 * 4 + r;
        dr[r] = (row < n) ? dinv[row] : 0.f;
    }
#pragma unroll
    for (int nt = 0; nt < 4; ++nt) {
        int col = nt * 16 + r16;
        short8 b = make_bfrag(W, kbase, col);
        f32x4 z = {0.f, 0.f, 0.f, 0.f};
        f32x4 acc = __builtin_amdgcn_mfma_f32_16x16x32_bf16(a, b, z, 0, 0, 0);
        float bcol = bias[col];
#pragma unroll
        for (int r = 0; r < 4; ++r) {
            int row = rowbase + g4 * 4 + r;
            float v = fmaxf(acc[r] + bcol, 0.f) * dr[r];
            float o = __shfl_xor(v, 1);
            if ((lane & 1) == 0)
                outw[((size_t)nt * npad + row) * 8 + (r16 >> 1)] = pack_bf16(v, o);
        }
    }
}

// pool[j] += sum_rows relu(A@W2 + b2); A sliced [4][npad][8w] (K=64); h2 never stored
__global__ __launch_bounds__(256) void gemm2_mfma_pool(const uint* __restrict__ A,
                                                       const float* __restrict__ W,
                                                       const float* __restrict__ bias,
                                                       float* __restrict__ g, int n, int npad) {
    __shared__ float sblk[64];
    int t = threadIdx.x;
    if (t < 64) sblk[t] = 0.f;
    __syncthreads();
    int lane = t & 63, wv = t >> 6;
    int rowbase = blockIdx.x * 64 + wv * 16;
    int r16 = lane & 15, g4 = lane >> 4;
    size_t roff = (size_t)(rowbase + r16) * 8 + (g4 & 1) * 4;
    size_t sstride = (size_t)npad * 8;
    short8 a0 = __builtin_bit_cast(short8,
        *reinterpret_cast<const uint4*>(A + (size_t)(g4 >> 1) * sstride + roff));
    short8 a1 = __builtin_bit_cast(short8,
        *reinterpret_cast<const uint4*>(A + (size_t)(2 + (g4 >> 1)) * sstride + roff));
#pragma unroll
    for (int nt = 0; nt < 4; ++nt) {
        int col = nt * 16 + r16;
        short8 b0 = make_bfrag(W, g4 * 8, col);
        short8 b1 = make_bfrag(W, 32 + g4 * 8, col);
        f32x4 z = {0.f, 0.f, 0.f, 0.f};
        f32x4 acc = __builtin_amdgcn_mfma_f32_16x16x32_bf16(a0, b0, z, 0, 0, 0);
        acc = __builtin_amdgcn_mfma_f32_16x16x32_bf16(a1, b1, acc, 0, 0, 0);
        float bcol = bias[col];
        float part = 0.f;
#pragma unroll
        for (int r = 0; r < 4; ++r) {
            int row = rowbase + g4 * 4 + r;
            float v = fmaxf(acc[r] + bcol, 0.f);
            part += (row < n) ? v : 0.f;
        }
        atomicAdd(&sblk[col], part);
    }
    __syncthreads();
    if (t < 64) atomicAdd(&g[t], sblk[t]);
}

__global__ void final_head(const float* __restrict__ g, const float* __restrict__ Wfc,
                           const float* __restrict__ bfc, float* __restrict__ out, int n) {
    __shared__ float logits[5];
    int t = threadIdx.x;
    if (t < 5) {
        float acc = bfc[t];
        float invn = 1.0f / (float)n;
        for (int k = 0; k < 64; ++k) acc += (g[k] * invn) * Wfc[k * 5 + t];
        logits[t] = acc;
    }
    __syncthreads();
    if (t == 0) {
        float m = logits[0];
        for (int i = 1; i < 5; ++i) m = fmaxf(m, logits[i]);
        float s = 0.0f;
        for (int i = 0; i < 5; ++i) s += expf(logits[i] - m);
        float lse = m + logf(s);
        for (int i = 0; i < 5; ++i) out[i] = logits[i] - lse;
    }
}

// ================= launch =================

extern "C" void kernel_launch(void* const* d_in, const int* in_sizes, int n_in,
                              void* d_out, int out_size, void* d_ws, size_t ws_size,
                              hipStream_t stream) {
    const float* x   = (const float*)d_in[0];
    const int*   ei  = (const int*)d_in[1];
    const float* W1  = (const float*)d_in[2];
    const float* b1  = (const float*)d_in[3];
    const float* W2  = (const float*)d_in[4];
    const float* b2  = (const float*)d_in[5];
    const float* Wfc = (const float*)d_in[6];
    const float* bfc = (const float*)d_in[7];
    float* out = (float*)d_out;

    const int n = in_sizes[0] / 32;   // 100000
    const int E = in_sizes[1] / 2;    // 1600000
    const int* src = ei;
    const int* dst = ei + E;
    const int npad = (n + 63) & ~63;
    const int nbucket = (n + 255) >> 8;
    const int chunk = (E + NBLK - 1) / NBLK;
    const int nchunk = (n + 63) / 64;

    // workspace carve-up (4-byte units)
    int*   csr_src = (int*)d_ws;                        // [E]
    int*   rowptr  = csr_src + E;                       // [n]
    int*   rowend  = rowptr + n;                        // [n]
    float* dinv    = (float*)(rowend + n);              // [n]
    int*   cnt     = (int*)(dinv + n);                  // [nbucket*NBLK]
    int*   totals  = cnt + (size_t)nbucket * NBLK;      // [nbucket+1]
    size_t offw    = (size_t)(totals + nbucket + 1 - (int*)d_ws);
    offw           = (offw + 3) & ~(size_t)3;           // 16B align
    uint*  xsl     = (uint*)d_ws + offw;                // [2*npad*8]
    uint*  agg1    = xsl + (size_t)2 * npad * 8;        // [2*npad*8]
    uint*  h1sl    = agg1 + (size_t)2 * npad * 8;       // [4*npad*8]
    uint*  agg2    = h1sl + (size_t)4 * npad * 8;       // [4*npad*8]
    float* g       = (float*)(agg2 + (size_t)4 * npad * 8); // [64]
    int*   bucketed = (int*)agg2;                       // alias: [E] consumed pre-agg (4*npad*8 >= E)

    const int B = 256;
    const size_t lds_b = (size_t)nbucket * sizeof(int);

    // ---- build CSR + norms (no global atomics) ----
    pass_hist<<<NBLK, B, lds_b, stream>>>(dst, cnt, E, nbucket, chunk);
    row_scan<<<nbucket, NBLK, 0, stream>>>(cnt, totals);
    total_scan<<<1, B, 0, stream>>>(totals, nbucket);
    pass_scatter<<<NBLK, B, lds_b, stream>>>(src, dst, cnt, totals, bucketed, E, nbucket, chunk);
    bucket_finalize<<<nbucket, B, 0, stream>>>(bucketed, totals, rowptr, rowend, dinv, csr_src, n);

    // ---- x -> pre-scaled sliced bf16 ----
    convert_x_sliced<<<(n * 2 + B - 1) / B, B, 0, stream>>>(x, dinv, xsl, n, npad);

    // ---- layer 1: sliced gather (2 slices) -> agg1; MFMA gemm -> h1' sliced [4] ----
    agg_gather_sliced<1><<<nchunk * 2, B, 0, stream>>>(rowptr, rowend, csr_src, dinv,
                                                       xsl, agg1, n, npad);
    gemm1_mfma<<<npad / 64, B, 0, stream>>>(agg1, W1, b1, dinv, h1sl, n, npad);

    // ---- layer 2: sliced gather (4 slices) -> agg2; MFMA gemm+relu+pool -> g ----
    agg_gather_sliced<2><<<nchunk * 4, B, 0, stream>>>(rowptr, rowend, csr_src, dinv,
                                                       h1sl, agg2, n, npad);
    hipMemsetAsync(g, 0, 64 * sizeof(float), stream);
    gemm2_mfma_pool<<<npad / 64, B, 0, stream>>>(agg2, W2, b2, g, n, npad);

    // ---- head ----
    final_head<<<1, 64, 0, stream>>>(g, Wfc, bfc, out, n);
}